// Round 14
// baseline (234.056 us; speedup 1.0000x reference)
//
#include <hip/hip_runtime.h>

#define L_SEQ 4096
#define DM    1024
#define NH    16
#define HD    64

typedef unsigned short ushort_t;
typedef __attribute__((ext_vector_type(8))) short bf16x8;
typedef __attribute__((ext_vector_type(4))) float f32x4;

__device__ inline unsigned short f2bf(float f) {
    union { float f; unsigned int u; } v; v.f = f;
    unsigned int r = v.u + 0x7fffu + ((v.u >> 16) & 1u);
    return (unsigned short)(r >> 16);
}

// pack two f32 -> two bf16 (RNE) in one instruction
__device__ inline unsigned cvt_pk_bf16(float lo, float hi) {
    unsigned w;
    asm("v_cvt_pk_bf16_f32 %0, %1, %2" : "=v"(w) : "v"(lo), "v"(hi));
    return w;
}

// raw v_exp_f32 (2^x). libm exp2f w/o -ffast-math carries OCML fixup code;
// our args are in [-1e30, ~40] where the raw instruction is exact enough
// (1 ULP; masked lanes -1e30 -> 0).
__device__ inline float ex2(float x) {
#if __has_builtin(__builtin_amdgcn_exp2f)
    return __builtin_amdgcn_exp2f(x);
#else
    return exp2f(x);
#endif
}

// async global->LDS, 16B/lane. LDS dest = wave-uniform base + lane*16.
__device__ inline void load_lds16(const ushort_t* g, ushort_t* l) {
    __builtin_amdgcn_global_load_lds(
        (const __attribute__((address_space(1))) unsigned int*)g,
        (__attribute__((address_space(3))) unsigned int*)l, 16, 0, 0);
}

// ---------------------------------------------------------------------------
// Runtime input-dtype detection (bf16 vs fp32 global buffers). Verified R3.
// ---------------------------------------------------------------------------
__device__ inline bool detect_f32(const ushort_t* xraw) {
    __shared__ int s_flag;
    const int t = threadIdx.x;
    if (t < 64) {
        unsigned e = (xraw[2 * t] >> 7) & 0xFFu;
        unsigned long long m = __ballot(e >= 0x88u);
        if (t == 0) s_flag = (__popcll(m) >= 8) ? 1 : 0;
    }
    __syncthreads();
    return s_flag != 0;
}

// ---------------------------------------------------------------------------
// Fused converts: z=0..3 -> weight z transposed bf16 wT[n][k]; z=4 -> x bf16.
// grid (16,16,5) x 256 thr.
// ---------------------------------------------------------------------------
__global__ __launch_bounds__(256) void convert_all(const void* __restrict__ xv,
                                                   const void* __restrict__ w0,
                                                   const void* __restrict__ w1,
                                                   const void* __restrict__ w2,
                                                   const void* __restrict__ w3,
                                                   ushort_t* __restrict__ xb,
                                                   ushort_t* __restrict__ wT) {
    bool f32 = detect_f32((const ushort_t*)xv);
    const int z = blockIdx.z;
    const int t = threadIdx.x;

    if (z == 4) {
        // x: 4M elems; 256 blocks x 8 iters x 256 thr x 8 elems
        const int B0 = (blockIdx.y * 16 + blockIdx.x) * 16384;
        #pragma unroll
        for (int it = 0; it < 8; ++it) {
            const int i = B0 + it * 2048 + t * 8;
            if (f32) {
                const float* xf = (const float*)xv;
                float4 v0 = *(const float4*)(xf + i);
                float4 v1 = *(const float4*)(xf + i + 4);
                uint4 u;
                u.x = cvt_pk_bf16(v0.x, v0.y);
                u.y = cvt_pk_bf16(v0.z, v0.w);
                u.z = cvt_pk_bf16(v1.x, v1.y);
                u.w = cvt_pk_bf16(v1.z, v1.w);
                *(uint4*)(xb + i) = u;
            } else {
                *(uint4*)(xb + i) = *(const uint4*)((const ushort_t*)xv + i);
            }
        }
        return;
    }

    const void* w = (z == 0) ? w0 : (z == 1) ? w1 : (z == 2) ? w2 : w3;
    ushort_t* out = wT + (size_t)z * (DM * DM);
    __shared__ ushort_t T[64][65];
    const int k0 = blockIdx.x * 64, n0 = blockIdx.y * 64;
    #pragma unroll
    for (int i = 0; i < 16; ++i) {
        int e = t + i * 256;
        int r = e >> 6, c = e & 63;
        T[r][c] = f32 ? f2bf(((const float*)w)[(size_t)(k0 + r) * DM + n0 + c])
                      : ((const ushort_t*)w)[(size_t)(k0 + r) * DM + n0 + c];
    }
    __syncthreads();
    #pragma unroll
    for (int i = 0; i < 16; ++i) {
        int e = t + i * 256;
        int d = e >> 6, l = e & 63;
        out[(size_t)(n0 + d) * DM + k0 + l] = T[l][d];
    }
}

// ---------------------------------------------------------------------------
// R14 GEMM: 64x128 TILE (M halved), BK=32 double-buffer. R11/R13 proved the
// 128x128 GEMM is latency-bound at 3 blocks/CU and schedule changes are
// neutral; the remaining lever is TLP. 64x128 => qkv grid 768->1536 =
// EXACTLY 6 blocks/CU (LDS 24 KB x 6 = 144 <= 160), ogemm 256->512 (2/CU).
// A-traffic/block halves (total unchanged); B-traffic doubles but B slice
// is L2-resident per XCD. 4 waves = 2(M) x 2(N), each owns 32x64 = acc[2][4].
// Swizzle identical to R13 (verified): lane l -> slab row l>>2, source
// granule (l&3)^(row&3); read position quad^(l15&3).
// cmode: 0 bf16, 1 f32, 2 bf16 transposed (Vt[d][L]).
// ---------------------------------------------------------------------------
__device__ inline void gemm64_body(const ushort_t* __restrict__ A,
                                   const ushort_t* __restrict__ Bt,
                                   void* __restrict__ Cv, int cmode,
                                   int m0, int n0) {
    constexpr int K = 1024, NOUT = 1024;
    __shared__ ushort_t As[2][64 * 32];    // [r][k], swizzled, 2 x 4 KB
    __shared__ ushort_t Bs[2][128 * 32];   // [r][k], swizzled, 2 x 8 KB

    const int t = threadIdx.x, lane = t & 63, wave = t >> 6;
    const int l15 = lane & 15, quad = lane >> 4;
    const int mw = (wave >> 1) * 32, nw = (wave & 1) * 64;
    const int srow = lane >> 2;                       // 0..15 within 16-row slab
    const int sgr  = (lane & 3) ^ (srow & 3);         // swizzled source granule
    const int rswz = l15 & 3;                         // read-side swizzle

    f32x4 acc[2][4] = {};

    auto stage = [&](int buf, int k0) {
        // A: 64x32 = 4 slabs, one per wave
        load_lds16(A + (size_t)(m0 + 16 * wave + srow) * K + k0 + sgr * 8,
                   &As[buf][16 * wave * 32]);
        // B: 128x32 = 8 slabs, two per wave
        #pragma unroll
        for (int i = 0; i < 2; ++i) {
            const int j = wave * 2 + i;
            load_lds16(Bt + (size_t)(n0 + 16 * j + srow) * K + k0 + sgr * 8,
                       &Bs[buf][16 * j * 32]);
        }
    };

    int par = 0;
    stage(0, 0);

    for (int ks = 0; ks < 32; ++ks) {
        __syncthreads();   // drains prefetch of buf[par]; prev reads of buf[par^1] done

        if (ks + 1 < 32) stage(par ^ 1, (ks + 1) * 32);

        bf16x8 af[2], bf[4];
        #pragma unroll
        for (int i = 0; i < 2; ++i)
            af[i] = *(const bf16x8*)&As[par][(mw + i * 16 + l15) * 32
                                             + ((quad ^ rswz) * 8)];
        #pragma unroll
        for (int i = 0; i < 4; ++i)
            bf[i] = *(const bf16x8*)&Bs[par][(nw + i * 16 + l15) * 32
                                             + ((quad ^ rswz) * 8)];
        #pragma unroll
        for (int mt = 0; mt < 2; ++mt)
            #pragma unroll
            for (int nt = 0; nt < 4; ++nt)
                acc[mt][nt] = __builtin_amdgcn_mfma_f32_16x16x32_bf16(
                    af[mt], bf[nt], acc[mt][nt], 0, 0, 0);
        par ^= 1;
    }

    if (cmode == 2) {
        // transposed write: Vt[col(d)][row(L)]; 4 acc regs = 4 consecutive L
        ushort_t* Vt = (ushort_t*)Cv;
        #pragma unroll
        for (int mt = 0; mt < 2; ++mt)
            #pragma unroll
            for (int nt = 0; nt < 4; ++nt) {
                int col  = n0 + nw + nt * 16 + l15;          // d
                int row0 = m0 + mw + mt * 16 + quad * 4;     // L (mult of 4)
                ushort_t pk[4] = {f2bf(acc[mt][nt][0]), f2bf(acc[mt][nt][1]),
                                  f2bf(acc[mt][nt][2]), f2bf(acc[mt][nt][3])};
                *(uint2*)&Vt[(size_t)col * L_SEQ + row0] = *(const uint2*)pk;
            }
        return;
    }

    // Paired epilogue: lanes l15 even/odd exchange one value so each lane
    // owns 2 consecutive cols of one row (even lane -> row mt=0, odd -> mt=1).
    const int odd = lane & 1;
    #pragma unroll
    for (int nt = 0; nt < 4; ++nt)
        #pragma unroll
        for (int r = 0; r < 4; ++r) {
            float zA = acc[0][nt][r];             // row mt=0, col l15
            float zB = acc[1][nt][r];             // row mt=1, col l15
            float send = odd ? zA : zB;
            float got  = __shfl_xor(send, 1);
            const int row = m0 + mw + odd * 16 + quad * 4 + r;
            const int col = n0 + nw + nt * 16 + (l15 & ~1);
            if (cmode == 1) {
                float2 w2 = odd ? make_float2(got, zB) : make_float2(zA, got);
                *(float2*)((float*)Cv + (size_t)row * NOUT + col) = w2;
            } else {
                float lo = odd ? got : zA;
                float hi = odd ? zB  : got;
                unsigned w = cvt_pk_bf16(lo, hi);
                *(unsigned*)((ushort_t*)Cv + (size_t)row * NOUT + col) = w;
            }
        }
}

// qkv: 1536 blocks (6/CU). Decode: n-tile = b&7 (fixed per XCD under
// round-robin -> weight slices stay in that XCD's L2); u = b>>3 (0..191);
// m0 = (u/3)*64, z = u%3 (z innermost: the 3 z-blocks of one (m,n) tile run
// adjacently on one XCD so z=1/z=2 re-read the x-tile from L2).
__global__ __launch_bounds__(256, 6) void qkv128(const ushort_t* __restrict__ xb,
                                                 const ushort_t* __restrict__ wT,
                                                 ushort_t* Qp, ushort_t* Kp, ushort_t* Vt) {
    const int b = blockIdx.x;
    const int n0 = (b & 7) * 128;
    const int u  = b >> 3;                 // 0..191
    const int m0 = (u / 3) * 64;
    const int z  = u % 3;
    const ushort_t* Bt = wT + (size_t)z * (DM * DM);
    if (z == 0)      gemm64_body(xb, Bt, Qp, 0, m0, n0);
    else if (z == 1) gemm64_body(xb, Bt, Kp, 0, m0, n0);
    else             gemm64_body(xb, Bt, Vt, 2, m0, n0);
}

__global__ __launch_bounds__(256, 6) void ogemm128(const void* __restrict__ xdet,
                                                   const ushort_t* __restrict__ An,
                                                   const ushort_t* __restrict__ woT,
                                                   void* __restrict__ C) {
    bool f32 = detect_f32((const ushort_t*)xdet);
    const int b = blockIdx.x;              // 0..511
    const int n0 = (b & 7) * 128, m0 = (b >> 3) * 64;
    gemm64_body(An, woT, C, f32 ? 1 : 0, m0, n0);
}

// ---------------------------------------------------------------------------
// Flash attention — R11 verified (89-91 us): QBLK=128, 512 thr (8 waves),
// grid 256 = 1 block/CU, all blocks exactly 33 tiles; fixed-base softmax,
// raw v_exp_f32, s_setprio around MFMA clusters. LDS 96 KB.
// ---------------------------------------------------------------------------
__global__ __launch_bounds__(512) void attn_kernel(const ushort_t* __restrict__ Q,
                                                   const ushort_t* __restrict__ Kp,
                                                   const ushort_t* __restrict__ Vt,
                                                   ushort_t* __restrict__ O) {
    __shared__ ushort_t Ks[2][128 * 64];   // [kv][d], swizzled, 2 x 16 KB
    __shared__ ushort_t Vs[2][64 * 128];   // [d][kv], swizzled, 2 x 16 KB
    __shared__ ushort_t Pt[128 * 128];     // [q][kv], swizzled,     32 KB

    const int b    = blockIdx.x;               // 0..255
    const int h    = 2 * (b & 7) + ((b >> 3) & 1);   // head: XCD L2 locality
    const int px   = b >> 4;                   // 0..15
    const int t    = threadIdx.x;
    const int lane = t & 63, wave = t >> 6;    // wave 0..7
    const int l15  = lane & 15, quad = lane >> 4;
    const float LOG2E  = 1.44269504f;
    const float slope2 = exp2f(-0.5f * (float)(h + 1)) * LOG2E;
    const float c0     = 0.125f * LOG2E;
    const float qd4f   = (float)(quad * 4);

    const int krow = lane >> 3, kgr = (lane & 7) ^ (lane >> 3);
    const int vsub = lane >> 4;
    const int swz = l15 & 7;

    auto stage_load = [&](int buf, int kv0) {
        #pragma unroll
        for (int i = 0; i < 2; ++i) {
            const int j = wave * 2 + i;            // K slab 0..15 (8 kv rows)
            const int r = 8 * j + krow;
            load_lds16(Kp + (size_t)(kv0 + r) * DM + h * HD + kgr * 8,
                       &Ks[buf][8 * j * 64]);
        }
        #pragma unroll
        for (int i = 0; i < 2; ++i) {
            const int j = wave * 2 + i;            // V slab 0..15 (4 d rows)
            const int d = 4 * j + vsub;
            const int g = (lane & 15) ^ (4 * (j & 1) + vsub);
            load_lds16(Vt + (size_t)(h * HD + d) * L_SEQ + kv0 + g * 8,
                       &Vs[buf][4 * j * 128]);
        }
    };

    int par = 0;
    stage_load(0, 0);

    #pragma unroll
    for (int half = 0; half < 2; ++half) {
        const int qb = half ? px : (31 - px);      // q128-block index
        const int q0 = qb * 128;
        const int qg = q0 + wave * 16 + l15;
        const float qf = (float)qg;
        const int nst = half ? (px + 1) : (32 - px);   // sum = 33 for all blocks

        bf16x8 bq[2];
        #pragma unroll
        for (int kt = 0; kt < 2; ++kt)
            bq[kt] = *(const bf16x8*)(Q + (size_t)qg * DM + h * HD + kt * 32 + quad * 8);

        f32x4 acc_o[4] = {};
        float l_r = 0.f;

        for (int s = 0; s < nst; ++s) {
            const int kv0 = s * 128;
            __syncthreads();

            const int nkv0 = (s + 1 < nst) ? (s + 1) * 128 : 0;
            stage_load(par ^ 1, nkv0);

            f32x4 sacc[8];
            #pragma unroll
            for (int mt = 0; mt < 8; ++mt) sacc[mt] = (f32x4){0.f, 0.f, 0.f, 0.f};
            __builtin_amdgcn_s_setprio(1);
            #pragma unroll
            for (int kt = 0; kt < 2; ++kt)
                #pragma unroll
                for (int mt = 0; mt < 8; ++mt) {
                    bf16x8 a = *(const bf16x8*)&Ks[par][(mt * 16 + l15) * 64
                                                        + (((kt * 4 + quad) ^ swz) * 8)];
                    sacc[mt] = __builtin_amdgcn_mfma_f32_16x16x32_bf16(a, bq[kt], sacc[mt], 0, 0, 0);
                }
            __builtin_amdgcn_s_setprio(0);

            const bool diag = (kv0 + 128 > q0);
            const float off = slope2 * ((float)kv0 + qd4f - qf);
            float rs = 0.f;
            #pragma unroll
            for (int mt = 0; mt < 8; ++mt)
                #pragma unroll
                for (int r = 0; r < 4; ++r) {
                    float kvl = (float)(mt * 16 + r);
                    float s2  = fmaf(sacc[mt][r], c0, fmaf(slope2, kvl, off));
                    if (diag) {
                        int kvg = kv0 + mt * 16 + quad * 4 + r;
                        s2 = (kvg <= qg) ? s2 : -1e30f;
                    }
                    float p = ex2(s2);              // fixed-base softmax, raw v_exp
                    sacc[mt][r] = p;
                    rs += p;
                }
            rs += __shfl_xor(rs, 16);
            rs += __shfl_xor(rs, 32);
            l_r += rs;

            #pragma unroll
            for (int mt = 0; mt < 8; ++mt) {
                union { float f; unsigned u; } a0, a1, a2, a3;
                a0.f = sacc[mt][0]; a1.f = sacc[mt][1];
                a2.f = sacc[mt][2]; a3.f = sacc[mt][3];
                uint2 w;
                w.x = __builtin_amdgcn_perm(a1.u, a0.u, 0x07060302);
                w.y = __builtin_amdgcn_perm(a3.u, a2.u, 0x07060302);
                const int g = mt * 2 + (quad >> 1);
                *(uint2*)&Pt[(wave * 16 + l15) * 128
                             + ((g ^ swz) * 8 + (quad & 1) * 4)] = w;
            }
            __threadfence_block();

            __builtin_amdgcn_s_setprio(1);
            #pragma unroll
            for (int kt = 0; kt < 4; ++kt) {
                bf16x8 a = *(const bf16x8*)&Pt[(wave * 16 + l15) * 128
                                               + (((kt * 4 + quad) ^ swz) * 8)];
                #pragma unroll
                for (int nt = 0; nt < 4; ++nt) {
                    bf16x8 bvv = *(const bf16x8*)&Vs[par][(nt * 16 + l15) * 128
                                                          + (((kt * 4 + quad) ^ swz) * 8)];
                    acc_o[nt] = __builtin_amdgcn_mfma_f32_16x16x32_bf16(a, bvv, acc_o[nt], 0, 0, 0);
                }
            }
            __builtin_amdgcn_s_setprio(0);

            par ^= 1;
        }

        float linv[4];
        #pragma unroll
        for (int r = 0; r < 4; ++r) linv[r] = 1.0f / __shfl(l_r, quad * 4 + r);
        #pragma unroll
        for (int nt = 0; nt < 4; ++nt)
            #pragma unroll
            for (int r = 0; r < 4; ++r) {
                int row = q0 + wave * 16 + quad * 4 + r;
                O[(size_t)row * DM + h * HD + nt * 16 + l15] = f2bf(acc_o[nt][r] * linv[r]);
            }
    }
}

// ---------------------------------------------------------------------------
extern "C" void kernel_launch(void* const* d_in, const int* in_sizes, int n_in,
                              void* d_out, int out_size, void* d_ws, size_t ws_size,
                              hipStream_t stream) {
    const void* x  = d_in[0];
    const void* wq = d_in[1];
    const void* wk = d_in[2];
    const void* wv = d_in[3];
    const void* wo = d_in[4];

    const size_t SZ = (size_t)L_SEQ * DM;   // 4M elems
    const size_t WZ = (size_t)DM * DM;      // 1M elems
    ushort_t* xb = (ushort_t*)d_ws;         // 8 MB
    ushort_t* wT = xb + SZ;                 // 4 x 2 MB
    ushort_t* Qp = wT + 4 * WZ;             // 8 MB
    ushort_t* Kp = Qp + SZ;                 // 8 MB
    ushort_t* Vt = Kp + SZ;                 // 8 MB  -> total 40 MB
    ushort_t* An = xb;                      // xb dead after qkv -> safe alias

    convert_all<<<dim3(16, 16, 5), 256, 0, stream>>>(x, wq, wk, wv, wo, xb, wT);
    qkv128<<<1536, 256, 0, stream>>>(xb, wT, Qp, Kp, Vt);
    attn_kernel<<<256, 512, 0, stream>>>(Qp, Kp, Vt, An);
    ogemm128<<<512, 256, 0, stream>>>(x, An, wT + 3 * WZ, d_out);
}

// Round 15
// 221.492 us; speedup vs baseline: 1.0567x; 1.0567x over previous
//
#include <hip/hip_runtime.h>

#define L_SEQ 4096
#define DM    1024
#define NH    16
#define HD    64

typedef unsigned short ushort_t;
typedef __attribute__((ext_vector_type(8))) short bf16x8;
typedef __attribute__((ext_vector_type(4))) float f32x4;

__device__ inline unsigned short f2bf(float f) {
    union { float f; unsigned int u; } v; v.f = f;
    unsigned int r = v.u + 0x7fffu + ((v.u >> 16) & 1u);
    return (unsigned short)(r >> 16);
}

// pack two f32 -> two bf16 (RNE) in one instruction
__device__ inline unsigned cvt_pk_bf16(float lo, float hi) {
    unsigned w;
    asm("v_cvt_pk_bf16_f32 %0, %1, %2" : "=v"(w) : "v"(lo), "v"(hi));
    return w;
}

// raw v_exp_f32 (2^x); exact enough for our domain (args <= ~40; -1e30 -> 0)
__device__ inline float ex2(float x) {
#if __has_builtin(__builtin_amdgcn_exp2f)
    return __builtin_amdgcn_exp2f(x);
#else
    return exp2f(x);
#endif
}

// async global->LDS, 16B/lane. LDS dest = wave-uniform base + lane*16.
__device__ inline void load_lds16(const ushort_t* g, ushort_t* l) {
    __builtin_amdgcn_global_load_lds(
        (const __attribute__((address_space(1))) unsigned int*)g,
        (__attribute__((address_space(3))) unsigned int*)l, 16, 0, 0);
}

// ---------------------------------------------------------------------------
// Runtime input-dtype detection (bf16 vs fp32 global buffers). Verified R3.
// ---------------------------------------------------------------------------
__device__ inline bool detect_f32(const ushort_t* xraw) {
    __shared__ int s_flag;
    const int t = threadIdx.x;
    if (t < 64) {
        unsigned e = (xraw[2 * t] >> 7) & 0xFFu;
        unsigned long long m = __ballot(e >= 0x88u);
        if (t == 0) s_flag = (__popcll(m) >= 8) ? 1 : 0;
    }
    __syncthreads();
    return s_flag != 0;
}

// ---------------------------------------------------------------------------
// Fused converts: z=0..3 -> weight z transposed bf16 wT[n][k]; z=4 -> x bf16.
// grid (16,16,5) x 256 thr.
// ---------------------------------------------------------------------------
__global__ __launch_bounds__(256) void convert_all(const void* __restrict__ xv,
                                                   const void* __restrict__ w0,
                                                   const void* __restrict__ w1,
                                                   const void* __restrict__ w2,
                                                   const void* __restrict__ w3,
                                                   ushort_t* __restrict__ xb,
                                                   ushort_t* __restrict__ wT) {
    bool f32 = detect_f32((const ushort_t*)xv);
    const int z = blockIdx.z;
    const int t = threadIdx.x;

    if (z == 4) {
        const int B0 = (blockIdx.y * 16 + blockIdx.x) * 16384;
        #pragma unroll
        for (int it = 0; it < 8; ++it) {
            const int i = B0 + it * 2048 + t * 8;
            if (f32) {
                const float* xf = (const float*)xv;
                float4 v0 = *(const float4*)(xf + i);
                float4 v1 = *(const float4*)(xf + i + 4);
                uint4 u;
                u.x = cvt_pk_bf16(v0.x, v0.y);
                u.y = cvt_pk_bf16(v0.z, v0.w);
                u.z = cvt_pk_bf16(v1.x, v1.y);
                u.w = cvt_pk_bf16(v1.z, v1.w);
                *(uint4*)(xb + i) = u;
            } else {
                *(uint4*)(xb + i) = *(const uint4*)((const ushort_t*)xv + i);
            }
        }
        return;
    }

    const void* w = (z == 0) ? w0 : (z == 1) ? w1 : (z == 2) ? w2 : w3;
    ushort_t* out = wT + (size_t)z * (DM * DM);
    __shared__ ushort_t T[64][65];
    const int k0 = blockIdx.x * 64, n0 = blockIdx.y * 64;
    #pragma unroll
    for (int i = 0; i < 16; ++i) {
        int e = t + i * 256;
        int r = e >> 6, c = e & 63;
        T[r][c] = f32 ? f2bf(((const float*)w)[(size_t)(k0 + r) * DM + n0 + c])
                      : ((const ushort_t*)w)[(size_t)(k0 + r) * DM + n0 + c];
    }
    __syncthreads();
    #pragma unroll
    for (int i = 0; i < 16; ++i) {
        int e = t + i * 256;
        int d = e >> 6, l = e & 63;
        out[(size_t)(n0 + d) * DM + k0 + l] = T[l][d];
    }
}

// ---------------------------------------------------------------------------
// R11 GEMM (verified best): BK=64, single-buffered, 128x128 tile.
// cmode: 0 bf16 row-major, 1 f32 row-major, 2 bf16 transposed (Vt[d][L]).
// ---------------------------------------------------------------------------
__device__ inline void gemm128_body(const ushort_t* __restrict__ A,
                                    const ushort_t* __restrict__ Bt,
                                    void* __restrict__ Cv, int cmode,
                                    int m0, int n0) {
    constexpr int K = 1024, NOUT = 1024;
    __shared__ ushort_t As[128 * 64];   // [r][k], swizzled, 16 KB
    __shared__ ushort_t Bs[128 * 64];

    const int t = threadIdx.x, lane = t & 63, wave = t >> 6;
    const int l15 = lane & 15, quad = lane >> 4;
    const int mw = (wave >> 1) * 64, nw = (wave & 1) * 64;
    const int srow = lane >> 3;
    const int sgr  = (lane & 7) ^ (lane >> 3);
    const int swz  = l15 & 7;

    f32x4 acc[4][4] = {};

    for (int k0 = 0; k0 < K; k0 += 64) {
        #pragma unroll
        for (int i = 0; i < 4; ++i) {
            const int j = wave * 4 + i;
            load_lds16(A  + (size_t)(m0 + 8 * j + srow) * K + k0 + sgr * 8,
                       &As[8 * j * 64]);
            load_lds16(Bt + (size_t)(n0 + 8 * j + srow) * K + k0 + sgr * 8,
                       &Bs[8 * j * 64]);
        }
        __syncthreads();

        #pragma unroll
        for (int kt = 0; kt < 2; ++kt) {
            bf16x8 af[4], bf[4];
            #pragma unroll
            for (int i = 0; i < 4; ++i) {
                af[i] = *(const bf16x8*)&As[(mw + i * 16 + l15) * 64
                                            + (((kt * 4 + quad) ^ swz) * 8)];
                bf[i] = *(const bf16x8*)&Bs[(nw + i * 16 + l15) * 64
                                            + (((kt * 4 + quad) ^ swz) * 8)];
            }
            #pragma unroll
            for (int mt = 0; mt < 4; ++mt)
                #pragma unroll
                for (int nt = 0; nt < 4; ++nt)
                    acc[mt][nt] = __builtin_amdgcn_mfma_f32_16x16x32_bf16(
                        af[mt], bf[nt], acc[mt][nt], 0, 0, 0);
        }
        __syncthreads();
    }

    if (cmode == 2) {
        ushort_t* Vt = (ushort_t*)Cv;
        #pragma unroll
        for (int mt = 0; mt < 4; ++mt)
            #pragma unroll
            for (int nt = 0; nt < 4; ++nt) {
                int col  = n0 + nw + nt * 16 + l15;
                int row0 = m0 + mw + mt * 16 + quad * 4;
                ushort_t pk[4] = {f2bf(acc[mt][nt][0]), f2bf(acc[mt][nt][1]),
                                  f2bf(acc[mt][nt][2]), f2bf(acc[mt][nt][3])};
                *(uint2*)&Vt[(size_t)col * L_SEQ + row0] = *(const uint2*)pk;
            }
        return;
    }

    const int odd = lane & 1;
    #pragma unroll
    for (int mtp = 0; mtp < 2; ++mtp)
        #pragma unroll
        for (int nt = 0; nt < 4; ++nt)
            #pragma unroll
            for (int r = 0; r < 4; ++r) {
                float zA = acc[2 * mtp][nt][r];
                float zB = acc[2 * mtp + 1][nt][r];
                float send = odd ? zA : zB;
                float got  = __shfl_xor(send, 1);
                const int row = m0 + mw + (2 * mtp + odd) * 16 + quad * 4 + r;
                const int col = n0 + nw + nt * 16 + (l15 & ~1);
                if (cmode == 1) {
                    float2 w2 = odd ? make_float2(got, zB) : make_float2(zA, got);
                    *(float2*)((float*)Cv + (size_t)row * NOUT + col) = w2;
                } else {
                    float lo = odd ? got : zA;
                    float hi = odd ? zB  : got;
                    unsigned w = cvt_pk_bf16(lo, hi);
                    *(unsigned*)((ushort_t*)Cv + (size_t)row * NOUT + col) = w;
                }
            }
}

// qkv: 768 blocks, z-innermost decode (verified R6).
__global__ __launch_bounds__(256) void qkv128(const ushort_t* __restrict__ xb,
                                              const ushort_t* __restrict__ wT,
                                              ushort_t* Qp, ushort_t* Kp, ushort_t* Vt) {
    const int b = blockIdx.x;
    const int n0 = (b & 7) * 128;
    const int u  = b >> 3;
    const int m0 = (u / 3) * 128;
    const int z  = u % 3;
    const ushort_t* Bt = wT + (size_t)z * (DM * DM);
    if (z == 0)      gemm128_body(xb, Bt, Qp, 0, m0, n0);
    else if (z == 1) gemm128_body(xb, Bt, Kp, 0, m0, n0);
    else             gemm128_body(xb, Bt, Vt, 2, m0, n0);
}

__global__ __launch_bounds__(256) void ogemm128(const void* __restrict__ xdet,
                                                const ushort_t* __restrict__ An,
                                                const ushort_t* __restrict__ woT,
                                                void* __restrict__ C) {
    bool f32 = detect_f32((const ushort_t*)xdet);
    const int b = blockIdx.x;
    const int n0 = (b & 7) * 128, m0 = (b >> 3) * 128;
    gemm128_body(An, woT, C, f32 ? 1 : 0, m0, n0);
}

// ---------------------------------------------------------------------------
// Flash attention — R11 verified (89-91 us). FALLBACK path (small workspace).
// ---------------------------------------------------------------------------
__global__ __launch_bounds__(512) void attn_kernel(const ushort_t* __restrict__ Q,
                                                   const ushort_t* __restrict__ Kp,
                                                   const ushort_t* __restrict__ Vt,
                                                   ushort_t* __restrict__ O) {
    __shared__ ushort_t Ks[2][128 * 64];
    __shared__ ushort_t Vs[2][64 * 128];
    __shared__ ushort_t Pt[128 * 128];

    const int b    = blockIdx.x;
    const int h    = 2 * (b & 7) + ((b >> 3) & 1);
    const int px   = b >> 4;
    const int t    = threadIdx.x;
    const int lane = t & 63, wave = t >> 6;
    const int l15  = lane & 15, quad = lane >> 4;
    const float LOG2E  = 1.44269504f;
    const float slope2 = exp2f(-0.5f * (float)(h + 1)) * LOG2E;
    const float c0     = 0.125f * LOG2E;
    const float qd4f   = (float)(quad * 4);

    const int krow = lane >> 3, kgr = (lane & 7) ^ (lane >> 3);
    const int vsub = lane >> 4;
    const int swz = l15 & 7;

    auto stage_load = [&](int buf, int kv0) {
        #pragma unroll
        for (int i = 0; i < 2; ++i) {
            const int j = wave * 2 + i;
            load_lds16(Kp + (size_t)(kv0 + 8 * j + krow) * DM + h * HD + kgr * 8,
                       &Ks[buf][8 * j * 64]);
        }
        #pragma unroll
        for (int i = 0; i < 2; ++i) {
            const int j = wave * 2 + i;
            const int d = 4 * j + vsub;
            const int g = (lane & 15) ^ (4 * (j & 1) + vsub);
            load_lds16(Vt + (size_t)(h * HD + d) * L_SEQ + kv0 + g * 8,
                       &Vs[buf][4 * j * 128]);
        }
    };

    int par = 0;
    stage_load(0, 0);

    #pragma unroll
    for (int half = 0; half < 2; ++half) {
        const int qb = half ? px : (31 - px);
        const int q0 = qb * 128;
        const int qg = q0 + wave * 16 + l15;
        const float qf = (float)qg;
        const int nst = half ? (px + 1) : (32 - px);

        bf16x8 bq[2];
        #pragma unroll
        for (int kt = 0; kt < 2; ++kt)
            bq[kt] = *(const bf16x8*)(Q + (size_t)qg * DM + h * HD + kt * 32 + quad * 8);

        f32x4 acc_o[4] = {};
        float l_r = 0.f;

        for (int s = 0; s < nst; ++s) {
            const int kv0 = s * 128;
            __syncthreads();

            const int nkv0 = (s + 1 < nst) ? (s + 1) * 128 : 0;
            stage_load(par ^ 1, nkv0);

            f32x4 sacc[8];
            #pragma unroll
            for (int mt = 0; mt < 8; ++mt) sacc[mt] = (f32x4){0.f, 0.f, 0.f, 0.f};
            __builtin_amdgcn_s_setprio(1);
            #pragma unroll
            for (int kt = 0; kt < 2; ++kt)
                #pragma unroll
                for (int mt = 0; mt < 8; ++mt) {
                    bf16x8 a = *(const bf16x8*)&Ks[par][(mt * 16 + l15) * 64
                                                        + (((kt * 4 + quad) ^ swz) * 8)];
                    sacc[mt] = __builtin_amdgcn_mfma_f32_16x16x32_bf16(a, bq[kt], sacc[mt], 0, 0, 0);
                }
            __builtin_amdgcn_s_setprio(0);

            const bool diag = (kv0 + 128 > q0);
            const float off = slope2 * ((float)kv0 + qd4f - qf);
            float rs = 0.f;
            #pragma unroll
            for (int mt = 0; mt < 8; ++mt)
                #pragma unroll
                for (int r = 0; r < 4; ++r) {
                    float kvl = (float)(mt * 16 + r);
                    float s2  = fmaf(sacc[mt][r], c0, fmaf(slope2, kvl, off));
                    if (diag) {
                        int kvg = kv0 + mt * 16 + quad * 4 + r;
                        s2 = (kvg <= qg) ? s2 : -1e30f;
                    }
                    float p = ex2(s2);
                    sacc[mt][r] = p;
                    rs += p;
                }
            rs += __shfl_xor(rs, 16);
            rs += __shfl_xor(rs, 32);
            l_r += rs;

            #pragma unroll
            for (int mt = 0; mt < 8; ++mt) {
                union { float f; unsigned u; } a0, a1, a2, a3;
                a0.f = sacc[mt][0]; a1.f = sacc[mt][1];
                a2.f = sacc[mt][2]; a3.f = sacc[mt][3];
                uint2 w;
                w.x = __builtin_amdgcn_perm(a1.u, a0.u, 0x07060302);
                w.y = __builtin_amdgcn_perm(a3.u, a2.u, 0x07060302);
                const int g = mt * 2 + (quad >> 1);
                *(uint2*)&Pt[(wave * 16 + l15) * 128
                             + ((g ^ swz) * 8 + (quad & 1) * 4)] = w;
            }
            __threadfence_block();

            __builtin_amdgcn_s_setprio(1);
            #pragma unroll
            for (int kt = 0; kt < 4; ++kt) {
                bf16x8 a = *(const bf16x8*)&Pt[(wave * 16 + l15) * 128
                                               + (((kt * 4 + quad) ^ swz) * 8)];
                #pragma unroll
                for (int nt = 0; nt < 4; ++nt) {
                    bf16x8 bvv = *(const bf16x8*)&Vs[par][(nt * 16 + l15) * 128
                                                          + (((kt * 4 + quad) ^ swz) * 8)];
                    acc_o[nt] = __builtin_amdgcn_mfma_f32_16x16x32_bf16(a, bvv, acc_o[nt], 0, 0, 0);
                }
            }
            __builtin_amdgcn_s_setprio(0);

            par ^= 1;
        }

        float linv[4];
        #pragma unroll
        for (int r = 0; r < 4; ++r) linv[r] = 1.0f / __shfl(l_r, quad * 4 + r);
        #pragma unroll
        for (int nt = 0; nt < 4; ++nt)
            #pragma unroll
            for (int r = 0; r < 4; ++r) {
                int row = q0 + wave * 16 + quad * 4 + r;
                O[(size_t)row * DM + h * HD + nt * 16 + l15] = f2bf(acc_o[nt][r] * linv[r]);
            }
    }
}

// ---------------------------------------------------------------------------
// R15 attn SPLIT: kv-parity decomposition, 2 blocks/CU.
// Fixed-base softmax => partials combine by ADDITION (no max/rescale).
// Grid 512: (b&255) = (h, px) as before; v = b>>8 processes tiles s=v,v+2,...
// of both q-halves. All blocks 16-17 tiles (uniform -> dispatch-order-proof).
// LDS single-buffer Ks 16K + Vs 16K + Pt 32K = 64K -> 2 blocks/CU (4 w/SIMD);
// co-resident paired block (same XCD, same head) hides staging latency and
// shares K/V tiles in L2. Partial O (f32, unnormalized) + l -> workspace.
// ---------------------------------------------------------------------------
__global__ __launch_bounds__(512, 4) void attn_split(const ushort_t* __restrict__ Q,
                                                     const ushort_t* __restrict__ Kp,
                                                     const ushort_t* __restrict__ Vt,
                                                     float* __restrict__ Op,
                                                     float* __restrict__ Lp) {
    __shared__ ushort_t Ks[128 * 64];   // 16 KB
    __shared__ ushort_t Vs[64 * 128];   // 16 KB
    __shared__ ushort_t Pt[128 * 128];  // 32 KB

    const int b    = blockIdx.x;               // 0..511
    const int bb   = b & 255;
    const int v    = b >> 8;                   // kv parity
    const int h    = 2 * (bb & 7) + ((bb >> 3) & 1);
    const int px   = bb >> 4;
    const int t    = threadIdx.x;
    const int lane = t & 63, wave = t >> 6;
    const int l15  = lane & 15, quad = lane >> 4;
    const float LOG2E  = 1.44269504f;
    const float slope2 = exp2f(-0.5f * (float)(h + 1)) * LOG2E;
    const float c0     = 0.125f * LOG2E;
    const float qd4f   = (float)(quad * 4);

    const int krow = lane >> 3, kgr = (lane & 7) ^ (lane >> 3);
    const int vsub = lane >> 4;
    const int swz = l15 & 7;

    float* Opv = Op + (size_t)v * L_SEQ * DM;

    auto stage_load = [&](int kv0) {
        #pragma unroll
        for (int i = 0; i < 2; ++i) {
            const int j = wave * 2 + i;
            load_lds16(Kp + (size_t)(kv0 + 8 * j + krow) * DM + h * HD + kgr * 8,
                       &Ks[8 * j * 64]);
        }
        #pragma unroll
        for (int i = 0; i < 2; ++i) {
            const int j = wave * 2 + i;
            const int d = 4 * j + vsub;
            const int g = (lane & 15) ^ (4 * (j & 1) + vsub);
            load_lds16(Vt + (size_t)(h * HD + d) * L_SEQ + kv0 + g * 8,
                       &Vs[4 * j * 128]);
        }
    };

    #pragma unroll
    for (int half = 0; half < 2; ++half) {
        const int qb = half ? px : (31 - px);
        const int q0 = qb * 128;
        const int qg = q0 + wave * 16 + l15;
        const float qf = (float)qg;
        const int nst = half ? (px + 1) : (32 - px);

        bf16x8 bq[2];
        #pragma unroll
        for (int kt = 0; kt < 2; ++kt)
            bq[kt] = *(const bf16x8*)(Q + (size_t)qg * DM + h * HD + kt * 32 + quad * 8);

        f32x4 acc_o[4] = {};
        float l_r = 0.f;

        for (int s = v; s < nst; s += 2) {
            const int kv0 = s * 128;
            stage_load(kv0);
            __syncthreads();                  // glds drained; prev compute done

            f32x4 sacc[8];
            #pragma unroll
            for (int mt = 0; mt < 8; ++mt) sacc[mt] = (f32x4){0.f, 0.f, 0.f, 0.f};
            __builtin_amdgcn_s_setprio(1);
            #pragma unroll
            for (int kt = 0; kt < 2; ++kt)
                #pragma unroll
                for (int mt = 0; mt < 8; ++mt) {
                    bf16x8 a = *(const bf16x8*)&Ks[(mt * 16 + l15) * 64
                                                   + (((kt * 4 + quad) ^ swz) * 8)];
                    sacc[mt] = __builtin_amdgcn_mfma_f32_16x16x32_bf16(a, bq[kt], sacc[mt], 0, 0, 0);
                }
            __builtin_amdgcn_s_setprio(0);

            const bool diag = (kv0 + 128 > q0);
            const float off = slope2 * ((float)kv0 + qd4f - qf);
            float rs = 0.f;
            #pragma unroll
            for (int mt = 0; mt < 8; ++mt)
                #pragma unroll
                for (int r = 0; r < 4; ++r) {
                    float kvl = (float)(mt * 16 + r);
                    float s2  = fmaf(sacc[mt][r], c0, fmaf(slope2, kvl, off));
                    if (diag) {
                        int kvg = kv0 + mt * 16 + quad * 4 + r;
                        s2 = (kvg <= qg) ? s2 : -1e30f;
                    }
                    float p = ex2(s2);          // fixed-base softmax
                    sacc[mt][r] = p;
                    rs += p;
                }
            rs += __shfl_xor(rs, 16);
            rs += __shfl_xor(rs, 32);
            l_r += rs;

            #pragma unroll
            for (int mt = 0; mt < 8; ++mt) {
                union { float f; unsigned u; } a0, a1, a2, a3;
                a0.f = sacc[mt][0]; a1.f = sacc[mt][1];
                a2.f = sacc[mt][2]; a3.f = sacc[mt][3];
                uint2 w;
                w.x = __builtin_amdgcn_perm(a1.u, a0.u, 0x07060302);
                w.y = __builtin_amdgcn_perm(a3.u, a2.u, 0x07060302);
                const int g = mt * 2 + (quad >> 1);
                *(uint2*)&Pt[(wave * 16 + l15) * 128
                             + ((g ^ swz) * 8 + (quad & 1) * 4)] = w;
            }
            __threadfence_block();

            __builtin_amdgcn_s_setprio(1);
            #pragma unroll
            for (int kt = 0; kt < 4; ++kt) {
                bf16x8 a = *(const bf16x8*)&Pt[(wave * 16 + l15) * 128
                                               + (((kt * 4 + quad) ^ swz) * 8)];
                #pragma unroll
                for (int nt = 0; nt < 4; ++nt) {
                    bf16x8 bvv = *(const bf16x8*)&Vs[(nt * 16 + l15) * 128
                                                     + (((kt * 4 + quad) ^ swz) * 8)];
                    acc_o[nt] = __builtin_amdgcn_mfma_f32_16x16x32_bf16(a, bvv, acc_o[nt], 0, 0, 0);
                }
            }
            __builtin_amdgcn_s_setprio(0);

            __syncthreads();                  // all waves done reading before next stage
        }

        // partial epilogue: UNNORMALIZED f32 O + row-sum l
        #pragma unroll
        for (int nt = 0; nt < 4; ++nt)
            #pragma unroll
            for (int r = 0; r < 4; ++r) {
                int row = q0 + wave * 16 + quad * 4 + r;
                Opv[(size_t)row * DM + h * HD + nt * 16 + l15] = acc_o[nt][r];
            }
        if (quad == 0)
            Lp[(size_t)v * (NH * L_SEQ) + (size_t)h * L_SEQ + qg] = l_r;
    }
}

// combine: An = (O0 + O1) / (l0 + l1), bf16. 2048 blocks x 256 thr x 8 elems.
__global__ __launch_bounds__(256) void attn_combine(const float* __restrict__ Op,
                                                    const float* __restrict__ Lp,
                                                    ushort_t* __restrict__ An) {
    const int i = (blockIdx.x * 256 + threadIdx.x) * 8;   // 0..4M-8
    const int row = i >> 10;
    const int h   = (i & 1023) >> 6;
    const float l0 = Lp[(size_t)h * L_SEQ + row];
    const float l1 = Lp[(size_t)NH * L_SEQ + (size_t)h * L_SEQ + row];
    const float linv = 1.0f / (l0 + l1);
    const size_t V1 = (size_t)L_SEQ * DM;
    float4 a0 = *(const float4*)(Op + i);
    float4 a1 = *(const float4*)(Op + i + 4);
    float4 b0 = *(const float4*)(Op + V1 + i);
    float4 b1 = *(const float4*)(Op + V1 + i + 4);
    uint4 u;
    u.x = cvt_pk_bf16((a0.x + b0.x) * linv, (a0.y + b0.y) * linv);
    u.y = cvt_pk_bf16((a0.z + b0.z) * linv, (a0.w + b0.w) * linv);
    u.z = cvt_pk_bf16((a1.x + b1.x) * linv, (a1.y + b1.y) * linv);
    u.w = cvt_pk_bf16((a1.z + b1.z) * linv, (a1.w + b1.w) * linv);
    *(uint4*)(An + i) = u;
}

// ---------------------------------------------------------------------------
extern "C" void kernel_launch(void* const* d_in, const int* in_sizes, int n_in,
                              void* d_out, int out_size, void* d_ws, size_t ws_size,
                              hipStream_t stream) {
    const void* x  = d_in[0];
    const void* wq = d_in[1];
    const void* wk = d_in[2];
    const void* wv = d_in[3];
    const void* wo = d_in[4];

    const size_t SZ = (size_t)L_SEQ * DM;   // 4M elems
    const size_t WZ = (size_t)DM * DM;      // 1M elems
    ushort_t* xb = (ushort_t*)d_ws;         // 8 MB
    ushort_t* wT = xb + SZ;                 // 4 x 2 MB
    ushort_t* Qp = wT + 4 * WZ;             // 8 MB
    ushort_t* Kp = Qp + SZ;                 // 8 MB
    ushort_t* Vt = Kp + SZ;                 // 8 MB  -> 40 MB so far
    ushort_t* An = xb;                      // xb dead after qkv -> safe alias

    float* Op = (float*)(Vt + SZ);          // 2 x 16 MB partial O (f32)
    float* Lp = Op + 2 * SZ;                // 2 x 256 KB partial l
    const size_t need = 40ull * 1024 * 1024 + 2 * SZ * 4 + 2ull * NH * L_SEQ * 4;

    convert_all<<<dim3(16, 16, 5), 256, 0, stream>>>(x, wq, wk, wv, wo, xb, wT);
    qkv128<<<768, 256, 0, stream>>>(xb, wT, Qp, Kp, Vt);
    if (ws_size >= need) {
        attn_split<<<512, 512, 0, stream>>>(Qp, Kp, Vt, Op, Lp);
        attn_combine<<<2048, 256, 0, stream>>>(Op, Lp, An);
    } else {
        attn_kernel<<<256, 512, 0, stream>>>(Qp, Kp, Vt, An);
    }
    ogemm128<<<256, 256, 0, stream>>>(x, An, wT + 3 * WZ, d_out);
}